// Round 10
// baseline (342.519 us; speedup 1.0000x reference)
//
#include <hip/hip_runtime.h>

// Fused GQA attention block: QKV proj(+RoPE, +V-transpose) -> flash attn -> out proj.
// B=2 S=2048 D=2048 H=16 KV=4 HD=128. All MFMA compute in bf16 (tol = 2% of max).

#define B_  2
#define S_  2048
#define D_  2048
#define H_  16
#define KV_ 4
#define HD_ 128
#define NQK 2560    // QK buffer row stride: 2048 (Q) + 512 (K); V goes to Vt directly

typedef unsigned short ushort_t;
typedef __attribute__((ext_vector_type(8))) __bf16 bf16x8;
typedef __attribute__((ext_vector_type(4))) float  f32x4;

__device__ __forceinline__ ushort_t f2bf(float f) {
    unsigned u = __float_as_uint(f);
    u += 0x7FFFu + ((u >> 16) & 1u);          // round-to-nearest-even
    return (ushort_t)(u >> 16);
}
__device__ __forceinline__ float bf2f(ushort_t h) {
    return __uint_as_float(((unsigned)h) << 16);
}

// async global->LDS, 16B per lane; LDS dest = wave-uniform base + lane*16
__device__ __forceinline__ void g2l16(const void* g, void* l) {
    __builtin_amdgcn_global_load_lds(
        (const __attribute__((address_space(1))) unsigned int*)g,
        (__attribute__((address_space(3))) unsigned int*)l, 16, 0, 0);
}

// ---------------- fused prep: x->bf16, 4 weight transposes, bias pack -------

__global__ __launch_bounds__(256) void k_prep(
    const float* __restrict__ x,  ushort_t* __restrict__ xb,
    const float* __restrict__ Wq, const float* __restrict__ Wk,
    const float* __restrict__ Wv, const float* __restrict__ Wo,
    ushort_t* __restrict__ Wt, ushort_t* __restrict__ Wot,
    const float* __restrict__ bq, const float* __restrict__ bk,
    const float* __restrict__ bv, float* __restrict__ bb) {
    __shared__ float tile[32][33];
    int id = blockIdx.x, t = threadIdx.x;
    if (id < 8192) {                                   // x fp32 -> bf16
        int i = id * 256 + t;
        float4 v = ((const float4*)x)[i];
        ushort4 o;
        o.x = f2bf(v.x); o.y = f2bf(v.y); o.z = f2bf(v.z); o.w = f2bf(v.w);
        ((ushort4*)xb)[i] = o;
        return;
    }
    const float* src; ushort_t* dst; int C, bid;
    if (id < 12288)      { src = Wq; dst = Wt;                       C = 2048; bid = id - 8192;  }
    else if (id < 13312) { src = Wk; dst = Wt + (size_t)2048 * 2048; C = 512;  bid = id - 12288; }
    else if (id < 14336) { src = Wv; dst = Wt + (size_t)2560 * 2048; C = 512;  bid = id - 13312; }
    else if (id < 18432) { src = Wo; dst = Wot;                      C = 2048; bid = id - 14336; }
    else {                                             // bias pack
        int i = (id - 18432) * 256 + t;
        if (i < 3072)
            bb[i] = (i < 2048) ? bq[i] : (i < 2560) ? bk[i - 2048] : bv[i - 2560];
        return;
    }
    const int R = 2048;
    int nbc = C >> 5;
    int c0 = (bid % nbc) * 32, r0 = (bid / nbc) * 32;
    int tx = t & 31, ty = t >> 5;
    for (int i = ty; i < 32; i += 8)
        tile[i][tx] = src[(size_t)(r0 + i) * C + c0 + tx];
    __syncthreads();
    for (int i = ty; i < 32; i += 8)
        dst[(size_t)(c0 + i) * R + r0 + tx] = f2bf(tile[tx][i]);
}

// ---------------- GEMM (r8 version, reverted from r9's regression) ----------
// 128x128 tile, templated BK (64 for gemm1 at 3 blk/CU; 128 for gemm2 whose
// 512-block grid is 2 blk/CU anyway). Homogeneous waves (r9's producer/consumer
// split halved MFMA-issuing waves without removing the barrier -> regressed).
// LDS: row-major 2*BK-byte rows; slot granule g holds global granule g^(row&7);
// staging writes sequential, fragment reads 2-way = free (r7: conflicts -> 0).
// XCD swizzle: block L -> xcd=L&7, m_tile striped per XCD (r6: FETCH 74->58).
// gemm1 (fc!=null): RoPE on cols<2560 pre-rounding; V cols -> transposed Vt.

template<int BK>
__global__ __launch_bounds__(256, 3) void k_gemm(const ushort_t* __restrict__ A,
                                                 const ushort_t* __restrict__ Bt,
                                                 void* __restrict__ Cp,
                                                 const float* __restrict__ bias,
                                                 const float* __restrict__ fc,
                                                 const float* __restrict__ fs,
                                                 ushort_t* __restrict__ Vt,
                                                 int M, int N, int K, int out_bf16) {
    constexpr int GPR    = BK / 8;    // 16B granules per row
    constexpr int RPR    = 64 / GPR;  // rows staged per round per wave
    constexpr int ROUNDS = 32 / RPR;  // rounds to cover 32 rows per wave
    __shared__ __align__(16) ushort_t As[128 * BK];
    __shared__ __align__(16) ushort_t Bs[128 * BK];
    int t = threadIdx.x;
    int w = t >> 6, lane = t & 63, quad = lane >> 4, l16 = lane & 15;
    int L = blockIdx.x;
    int mper = (M >> 7) >> 3;                 // m-tiles per XCD
    int xcd = L & 7, j = L >> 3;
    int m0 = (xcd * mper + (j % mper)) * 128;
    int n0 = (j / mper) * 128;
    int wm = (w >> 1) * 64, wn = (w & 1) * 64;
    f32x4 acc[4][4] = {};

    int rlo = lane / GPR;                     // row-within-round
    int gsl = lane & (GPR - 1);               // slot granule
    const ushort_t* Ag = A  + (size_t)(m0 + w * 32) * K;
    const ushort_t* Bg = Bt + (size_t)(n0 + w * 32) * K;
    int rsw = (l16 & 7);                      // read-side swizzle bits

    for (int k0 = 0; k0 < K; k0 += BK) {
        __syncthreads();
#pragma unroll
        for (int p = 0; p < ROUNDS; p++) {
            int row = p * RPR + rlo;
            int gs = gsl ^ (row & 7);
            g2l16(Ag + (size_t)row * K + k0 + gs * 8, (char*)As + (w * 32 + p * RPR) * 2 * BK);
            g2l16(Bg + (size_t)row * K + k0 + gs * 8, (char*)Bs + (w * 32 + p * RPR) * 2 * BK);
        }
        __syncthreads();
#pragma unroll
        for (int kc = 0; kc < BK / 32; kc++) {
            int gg = quad + kc * 4;
            bf16x8 af[4], bfr[4];
#pragma unroll
            for (int i = 0; i < 4; i++)
                af[i] = *(const bf16x8*)(As + (wm + i * 16 + l16) * BK + ((gg ^ rsw) * 8));
#pragma unroll
            for (int j2 = 0; j2 < 4; j2++)
                bfr[j2] = *(const bf16x8*)(Bs + (wn + j2 * 16 + l16) * BK + ((gg ^ rsw) * 8));
#pragma unroll
            for (int i = 0; i < 4; i++)
#pragma unroll
                for (int j2 = 0; j2 < 4; j2++)
                    acc[i][j2] = __builtin_amdgcn_mfma_f32_16x16x32_bf16(af[i], bfr[j2], acc[i][j2], 0, 0, 0);
        }
    }
    // epilogue: C/D layout col=lane&15, row=quad*4+reg
    int ostride = fc ? NQK : N;               // gemm1 writes QK buffer (stride 2560)
#pragma unroll
    for (int i = 0; i < 4; i++) {
        int r = m0 + wm + i * 16 + quad * 4;
#pragma unroll
        for (int j2 = 0; j2 < 4; j2++) {
            int c = n0 + wn + j2 * 16 + l16;
            float bv_ = bias ? bias[c] : 0.f;
            if (fc && c >= 2560) {                    // V cols -> transposed to Vt
                ushort4 pack;
                pack.x = f2bf(acc[i][j2][0] + bv_);
                pack.y = f2bf(acc[i][j2][1] + bv_);
                pack.z = f2bf(acc[i][j2][2] + bv_);
                pack.w = f2bf(acc[i][j2][3] + bv_);
                int kv = (c - 2560) >> 7, d = (c - 2560) & 127;
                int b = r >> 11, s0 = r & (S_ - 1);
                *(ushort4*)&Vt[(((size_t)b * KV_ + kv) * HD_ + d) * S_ + s0] = pack;
                continue;
            }
#pragma unroll
            for (int jr = 0; jr < 4; jr++) {
                float v = acc[i][j2][jr] + bv_;
                if (fc) {                             // fused RoPE on Q,K cols
                    int s  = (r + jr) & (S_ - 1);
                    int dp = (c & 127) >> 1;
                    float cs = fc[s * 64 + dp], sn = fs[s * 64 + dp];
                    float p = __shfl_xor(v, 1);       // pair element (c^1)
                    v = (c & 1) ? (v * cs + p * sn) : (v * cs - p * sn);
                }
                if (out_bf16) ((ushort_t*)Cp)[(size_t)(r + jr) * ostride + c] = f2bf(v);
                else          ((float*)Cp)[(size_t)(r + jr) * ostride + c] = v;
            }
        }
    }
}

// ---------------- Flash attention v6: 32 q-rows per wave --------------------
// r10: flash was LDS-read-bound (~34 b128 reads per 34 MFFMA = 15 FLOP/B,
// ~45 us of pure LDS traffic). Now 256-thread blocks, 4 waves, wave w owns
// 32 q rows (2 row-blocks of 16): every K/V fragment read feeds 2 MFMAs ->
// 36 reads per 68 MFMA = 30 FLOP/B, halving LDS traffic. All waves stage both
// K and V (8 g2l16 each; chunk maps byte-identical to v5). Double-buffered,
// XOR bank swizzle, max-free softmax, l via ones-B MFMA. LDS 80 KB, grid
// 512 blocks = 2 blocks/CU. launch_bounds(256,2): 256-VGPR cap (need ~160).

__global__ __launch_bounds__(256, 2) void k_flash(const ushort_t* __restrict__ QK,
                                                  const ushort_t* __restrict__ Vt,
                                                  ushort_t* __restrict__ AO) {
    __shared__ __align__(16) ushort_t Ks[2 * 8192];
    __shared__ __align__(16) ushort_t Vs[2 * 8192];
    __shared__ __align__(16) ushort_t Ps[4 * 32 * 64];
    int h = blockIdx.y, b = blockIdx.z;
    int qt = b ? ((int)gridDim.x - 1 - (int)blockIdx.x) : (int)blockIdx.x;
    int kvh = h >> 2;
    int t = threadIdx.x, w = t >> 6, lane = t & 63, quad = lane >> 4, l16 = lane & 15;
    int qrow0 = qt * 128 + w * 32;            // this wave's first q row (owns 32)
    const float SOFT = 0.08838834764831845f * 1.4426950408889634f; // 1/sqrt(128)*log2(e)

    bf16x8 aq[2][4];
#pragma unroll
    for (int rb = 0; rb < 2; rb++) {
        const ushort_t* qb = QK + (size_t)(b * S_ + qrow0 + rb * 16 + l16) * NQK + h * HD_ + quad * 8;
#pragma unroll
        for (int kc = 0; kc < 4; kc++) aq[rb][kc] = *(const bf16x8*)(qb + kc * 32);
    }
    bf16x8 vone;
#pragma unroll
    for (int i = 0; i < 8; i++) vone[i] = (__bf16)1.0f;

    f32x4 o[2][8] = {};
    f32x4 ol[2] = {};              // row-sum accumulators (softmax denominator)
    ushort_t* Psw = Ps + w * 32 * 64;
    int gsw = (l16 >> 1) & 3;      // read-side swizzle bits

    const ushort_t* kgb = QK + (size_t)(b * S_) * NQK + 2048 + kvh * HD_;
    const ushort_t* vgb = Vt + ((size_t)(b * KV_ + kvh) * HD_) * S_;

    int sr  = t >> 2;                          // staging row (0..63)
    int sgs = (t & 3) ^ ((sr >> 1) & 3);       // staging granule (bank swizzle)
    char* sK0 = (char*)Ks + w * 1024;
    char* sV0 = (char*)Vs + w * 1024;

#define STAGE(KT, BUF)                                                          \
    do {                                                                        \
        const ushort_t* kg = kgb + (size_t)((KT) * 64 + sr) * NQK + sgs * 8;    \
        const ushort_t* vg = vgb + (KT) * 64 + sgs * 8 + (size_t)sr * S_;       \
        _Pragma("unroll")                                                       \
        for (int p = 0; p < 4; p++) {                                           \
            g2l16(kg + p * 32, sK0 + (BUF) * 16384 + p * 4096);                 \
            g2l16(vg + (size_t)((p & 1) * 64) * S_ + (p >> 1) * 32,             \
                  sV0 + (BUF) * 16384 + p * 4096);                              \
        }                                                                       \
    } while (0)

    int ktmax = 2 * qt + 1;
    STAGE(0, 0);
    __syncthreads();

    for (int kt = 0; kt <= ktmax; kt++) {
        int cur = kt & 1;
        if (kt < ktmax) STAGE(kt + 1, cur ^ 1);   // prefetch next tile

        if (kt * 64 <= qrow0 + 31) {              // else fully-masked for this wave
            const ushort_t* Kc = Ks + cur * 8192;
            const ushort_t* Vc = Vs + cur * 8192;
            // scores: S = Q @ K^T ; each bk read feeds both row-blocks
            f32x4 sacc[2][4] = {};
#pragma unroll
            for (int kc = 0; kc < 4; kc++)
#pragma unroll
                for (int nb = 0; nb < 4; nb++) {
                    bf16x8 bk = *(const bf16x8*)(Kc + kc * 2048 + (nb * 16 + l16) * 32 + ((quad ^ gsw) * 8));
                    sacc[0][nb] = __builtin_amdgcn_mfma_f32_16x16x32_bf16(aq[0][kc], bk, sacc[0][nb], 0, 0, 0);
                    sacc[1][nb] = __builtin_amdgcn_mfma_f32_16x16x32_bf16(aq[1][kc], bk, sacc[1][nb], 0, 0, 0);
                }
            if (kt * 64 + 63 > qrow0) {           // diagonal region: causal mask
#pragma unroll
                for (int rb = 0; rb < 2; rb++)
#pragma unroll
                    for (int nb = 0; nb < 4; nb++)
#pragma unroll
                        for (int jr = 0; jr < 4; jr++) {
                            int kcol = kt * 64 + nb * 16 + l16;
                            int qr = qrow0 + rb * 16 + quad * 4 + jr;
                            if (kcol > qr) sacc[rb][nb][jr] = -1e30f;
                        }
            }
            // unnormalized probs
#pragma unroll
            for (int rb = 0; rb < 2; rb++)
#pragma unroll
                for (int nb = 0; nb < 4; nb++)
#pragma unroll
                    for (int jr = 0; jr < 4; jr++)
                        Psw[(rb * 16 + quad * 4 + jr) * 64 + nb * 16 + l16] =
                            f2bf(exp2f(sacc[rb][nb][jr] * SOFT));

            asm volatile("s_waitcnt lgkmcnt(0)" ::: "memory");  // P writes -> A-frag reads

            // O += P @ V ; l += P @ ones ; each bv read feeds both row-blocks
#pragma unroll
            for (int kc2 = 0; kc2 < 2; kc2++) {
                bf16x8 ap0 = *(const bf16x8*)(Psw + l16 * 64 + kc2 * 32 + quad * 8);
                bf16x8 ap1 = *(const bf16x8*)(Psw + (16 + l16) * 64 + kc2 * 32 + quad * 8);
                ol[0] = __builtin_amdgcn_mfma_f32_16x16x32_bf16(ap0, vone, ol[0], 0, 0, 0);
                ol[1] = __builtin_amdgcn_mfma_f32_16x16x32_bf16(ap1, vone, ol[1], 0, 0, 0);
#pragma unroll
                for (int db = 0; db < 8; db++) {
                    bf16x8 bv = *(const bf16x8*)(Vc + kc2 * 4096 + (db * 16 + l16) * 32 + ((quad ^ gsw) * 8));
                    o[0][db] = __builtin_amdgcn_mfma_f32_16x16x32_bf16(ap0, bv, o[0][db], 0, 0, 0);
                    o[1][db] = __builtin_amdgcn_mfma_f32_16x16x32_bf16(ap1, bv, o[1][db], 0, 0, 0);
                }
            }
        }
        __syncthreads();   // next tile staged + this tile's LDS reads done
    }
#undef STAGE

    // epilogue: divide by l, write bf16
#pragma unroll
    for (int rb = 0; rb < 2; rb++)
#pragma unroll
        for (int jr = 0; jr < 4; jr++) {
            float inv = 1.0f / ol[rb][jr];
            size_t rbase = (size_t)(b * S_ + qrow0 + rb * 16 + quad * 4 + jr) * D_ + h * HD_;
#pragma unroll
            for (int db = 0; db < 8; db++)
                AO[rbase + db * 16 + l16] = f2bf(o[rb][db][jr] * inv);
        }
}

// ---------------- launch ----------------

extern "C" void kernel_launch(void* const* d_in, const int* in_sizes, int n_in,
                              void* d_out, int out_size, void* d_ws, size_t ws_size,
                              hipStream_t stream) {
    const float* x  = (const float*)d_in[0];
    // d_in[1] = mask (all zeros; reference ignores it — causal built in-kernel)
    const float* fc = (const float*)d_in[2];
    const float* fs = (const float*)d_in[3];
    const float* Wq = (const float*)d_in[4];
    const float* bq = (const float*)d_in[5];
    const float* Wk = (const float*)d_in[6];
    const float* bk = (const float*)d_in[7];
    const float* Wv = (const float*)d_in[8];
    const float* bv = (const float*)d_in[9];
    const float* Wo = (const float*)d_in[10];

    char* ws = (char*)d_ws;
    // layout (bytes); AO aliases xb (xb dead after gemm1). Vt is its own 4 MB
    // (must NOT alias Wt: gemm1 reads Wt while writing Vt). QK stride 2560.
    ushort_t* xb  = (ushort_t*)(ws);                 // 16 MB  (4096x2048 bf16)
    ushort_t* Wt  = (ushort_t*)(ws + 16777216);      // 12 MB  (3072x2048 bf16)
    ushort_t* Wot = (ushort_t*)(ws + 29360128);      //  8 MB  (2048x2048 bf16)
    float*    bb  = (float*)   (ws + 37748736);      // 12 KB
    ushort_t* QK  = (ushort_t*)(ws + 37761024);      // 20 MB  (4096x2560 bf16)
    ushort_t* Vt  = (ushort_t*)(ws + 58732544);      //  4 MB  (2*4*128*2048 bf16)
    ushort_t* AO  = xb;                              // 16 MB  (4096x2048 bf16)
    float* out = (float*)d_out;

    k_prep<<<18444, 256, 0, stream>>>(x, xb, Wq, Wk, Wv, Wo, Wt, Wot, bq, bk, bv, bb);
    k_gemm<64><<<768, 256, 0, stream>>>(xb, Wt, QK, bb, fc, fs, Vt, 4096, 3072, 2048, 1);
    k_flash<<<dim3(16, 16, 2), 256, 0, stream>>>(QK, Vt, AO);
    k_gemm<128><<<512, 256, 0, stream>>>(AO, Wot, out, nullptr, nullptr, nullptr, nullptr,
                                         4096, 2048, 2048, 0);
}